// Round 26
// baseline (235.268 us; speedup 1.0000x reference)
//
#include <hip/hip_runtime.h>
#include <hip/hip_fp16.h>

using i32x2  = __attribute__((ext_vector_type(2)))  int;
using i32x4  = __attribute__((ext_vector_type(4)))  int;
using i32x16 = __attribute__((ext_vector_type(16))) int;

static constexpr int M  = 4 * 2048;   // 8192 rows (B*S)
static constexpr int N  = 4096;       // OUT_F
static constexpr int K  = 4096;       // IN_F
static constexpr int NT = K / 64;     // 64 K-tiles
static constexpr int NS = K / 256;    // 16 slots (4 K-tiles each)
static constexpr int ATILE = 256 * 64;  // 16 KB packed A tile (256-row)
static constexpr int BTILE = 128 * 64;  //  8 KB packed B tile (128-col)

// ---------------- fused pack kernel: int32 -> blocked int8 tiles -------------
// A tile (16 KB): [kg(4)][row(256)][16B]   wa: [M/256][NT][ATILE]
// B tile ( 8 KB): [kg(4)][col(128)][16B]   wb: [N/128][NT][BTILE] (transposed)
// pack_x: one block = 64 rows x 64 k; coalesced read, LDS transpose, 1KB-run writes.
static constexpr int PX_BLOCKS = 32 * 4 * 64;                      // 8192
static constexpr int PW_BLOCKS = (int)((size_t)N * K / 16 / 256);  // 4096

__device__ __forceinline__ unsigned pack4(i32x4 v) {
  return (unsigned)((v.x & 255) | ((v.y & 255) << 8) | ((v.z & 255) << 16) | (v.w << 24));
}

__global__ __launch_bounds__(256) void pack_kernel(const int* __restrict__ x,
                                                   const int* __restrict__ w,
                                                   unsigned char* __restrict__ wa,
                                                   unsigned char* __restrict__ wb) {
  __shared__ __align__(16) unsigned char lds[64 * 72];   // 72-B row stride

  if (blockIdx.x < PX_BLOCKS) {
    const int b      = blockIdx.x;
    const int br     = b >> 8;           // 0..31
    const int rowblk = (b >> 6) & 3;     // 0..3  (64-row slab)
    const int kt     = b & 63;           // 0..63 (K-tile)
    const int t      = threadIdx.x;

    // read: thread t -> row (t>>2), k-chunk (t&3)*16; 64 B contiguous per thread
    const int rrow = t >> 2, rch = t & 3;
    const int* src = x + (size_t)(br * 256 + rowblk * 64 + rrow) * K
                       + kt * 64 + rch * 16;
    i32x4 v0 = *(const i32x4*)(src + 0);
    i32x4 v1 = *(const i32x4*)(src + 4);
    i32x4 v2 = *(const i32x4*)(src + 8);
    i32x4 v3 = *(const i32x4*)(src + 12);
    i32x2 lo, hi;
    lo.x = (int)pack4(v0); lo.y = (int)pack4(v1);
    hi.x = (int)pack4(v2); hi.y = (int)pack4(v3);
    *(i32x2*)(lds + rrow * 72 + rch * 16 + 0) = lo;
    *(i32x2*)(lds + rrow * 72 + rch * 16 + 8) = hi;
    __syncthreads();

    // write: thread t -> kg (t>>6), row (t&63); dest contiguous across lanes
    const int kg = t >> 6, wrow = t & 63;
    i32x2 a = *(const i32x2*)(lds + wrow * 72 + kg * 16 + 0);
    i32x2 c = *(const i32x2*)(lds + wrow * 72 + kg * 16 + 8);
    i32x4 d; d.x = a.x; d.y = a.y; d.z = c.x; d.w = c.y;
    unsigned char* dst = wa + (size_t)(br * 64 + kt) * 16384
                            + (kg * 256 + rowblk * 64 + wrow) * 16;
    *(i32x4*)dst = d;
  } else {
    unsigned g = (blockIdx.x - PX_BLOCKS) * 256 + threadIdx.x;  // < N*K/16
    unsigned col = g & 127;
    unsigned kg  = (g >> 7) & 3;
    unsigned kt  = (g >> 9) & 63;
    unsigned bn  = g >> 15;
    unsigned n   = bn * 128 + col;
    unsigned k0  = kt * 64 + kg * 16;
    const int* src = w + (size_t)k0 * N + n;
    i32x4 d;
#pragma unroll
    for (int j = 0; j < 4; ++j) {
      int b0 = src[(size_t)(j * 4 + 0) * N];
      int b1 = src[(size_t)(j * 4 + 1) * N];
      int b2 = src[(size_t)(j * 4 + 2) * N];
      int b3 = src[(size_t)(j * 4 + 3) * N];
      d[j] = (b0 & 255) | ((b1 & 255) << 8) | ((b2 & 255) << 16) | (b3 << 24);
    }
    *(i32x4*)(wb + (size_t)g * 16) = d;
  }
}

// -- GEMM: R20 structure + EXPLICIT A-FRAG SOFTWARE PIPELINE. ----------------
// Producer-consumer, quad-tile slots (BK=256), 2-slot ring, 128 KB LDS.
// Block 256x128, 512 thr. Waves 0-3: consumers (2x2 grid, wave 128x64,
//   acc[4][2]); chunk c+1's 4 ds_read_b128 issued BEFORE chunk c's 8 MFMAs
//   (alternating P/Q frag sets) so LDS return latency hides under MFMA.
//   No setprio (suspected scheduler fence). Waves 4-7: producers (16
//   gload_lds each). One barrier per slot. B direct L2->VGPR, parity dbuf.

__device__ __forceinline__ void gload_lds16(const void* g, void* l) {
  __builtin_amdgcn_global_load_lds((const __attribute__((address_space(1))) unsigned int*)g,
                                   (__attribute__((address_space(3))) unsigned int*)l,
                                   16, 0, 0);
}

#define FENCE()   asm volatile("" ::: "memory")
#define BARRIER() do { FENCE(); __builtin_amdgcn_s_barrier(); FENCE(); } while (0)

__global__ __launch_bounds__(512, 1) void gemm_i8(const unsigned char* __restrict__ wa,
                                                  const unsigned char* __restrict__ wb,
                                                  const __half* __restrict__ bias,
                                                  const float* __restrict__ alphaP,
                                                  float* __restrict__ out) {
  __shared__ __align__(16) unsigned char As[2][65536];   // 128 KB: 2 slots x 4 A-tiles

  const int tid  = threadIdx.x;
  const int lane = tid & 63;
  const int w    = tid >> 6;            // wave 0..7
  const int cw   = w & 3;
  const int l31  = lane & 31;
  const int kgl  = lane >> 5;

  const int bc = blockIdx.x;            // 0..31 (N/128)
  const int br = blockIdx.y;            // 0..31 (M/256)

  const unsigned char* ga = wa + (size_t)br * NT * ATILE;   // 256-row A panel

  if (w >= 4) {
    // ------------------------- PRODUCER (1 per SIMD) -----------------------
    const int poff = cw * 16384;        // this wave's 16 KB of the 64 KB slot

#define STAGE(S) do {                                                          \
      const unsigned char* src = ga + (size_t)(S) * 65536 + poff + lane * 16;  \
      unsigned char* dst = &As[(S) & 1][poff];                                 \
      _Pragma("unroll")                                                        \
      for (int j = 0; j < 16; ++j)                                             \
        gload_lds16(src + j * 1024, dst + j * 1024);                           \
    } while (0)

    STAGE(0);
    asm volatile("s_waitcnt vmcnt(0)" ::: "memory");
    BARRIER();                           // slot 0 ready
    for (int s = 0; s < NS; ++s) {
      if (s + 1 < NS) {
        STAGE(s + 1);                    // slot (s+1)&1 was freed at barrier s-1
        asm volatile("s_waitcnt vmcnt(0)" ::: "memory");
      }
      BARRIER();                         // end of step s: slot s+1 resident
    }
#undef STAGE
    return;   // producers skip epilogue
  }

  // --------------------------- CONSUMER (1 per SIMD) -----------------------
  const int cr = cw >> 1, cc = cw & 1;  // 2 x 2 grid; wave tile 128 x 64
  const int arow = cr * 128 + l31;      // A frag row base
  const int bcol = cc * 64 + l31;       // B frag col base (within 128-panel)

  const unsigned char* gbw = wb + (size_t)bc * NT * BTILE;  // 128-col B panel

  i32x4 b[2][2][2];                     // [parity][kc][ni] — const indices
  i32x4 aP0, aP1, aP2, aP3;             // frag set P (even chunks)
  i32x4 aQ0, aQ1, aQ2, aQ3;             // frag set Q (odd chunks)
  i32x16 acc[4][2] = {};

#define BLOAD(PAR, T) do {                                                     \
    const unsigned char* bt = gbw + (size_t)(T) * BTILE;                       \
    b[PAR][0][0] = *(const i32x4*)(bt + (kgl)     * 2048 + (bcol +  0) * 16);  \
    b[PAR][0][1] = *(const i32x4*)(bt + (kgl)     * 2048 + (bcol + 32) * 16);  \
    b[PAR][1][0] = *(const i32x4*)(bt + (2 + kgl) * 2048 + (bcol +  0) * 16);  \
    b[PAR][1][1] = *(const i32x4*)(bt + (2 + kgl) * 2048 + (bcol + 32) * 16);  \
  } while (0)

#define READF_P(TOFF, KC) do {                                                 \
    const unsigned char* Ap = slot + (TOFF) + ((KC) * 2 + kgl) * 4096;         \
    aP0 = *(const i32x4*)(Ap + (arow +  0) * 16);                              \
    aP1 = *(const i32x4*)(Ap + (arow + 32) * 16);                              \
    aP2 = *(const i32x4*)(Ap + (arow + 64) * 16);                              \
    aP3 = *(const i32x4*)(Ap + (arow + 96) * 16);                              \
  } while (0)

#define READF_Q(TOFF, KC) do {                                                 \
    const unsigned char* Ap = slot + (TOFF) + ((KC) * 2 + kgl) * 4096;         \
    aQ0 = *(const i32x4*)(Ap + (arow +  0) * 16);                              \
    aQ1 = *(const i32x4*)(Ap + (arow + 32) * 16);                              \
    aQ2 = *(const i32x4*)(Ap + (arow + 64) * 16);                              \
    aQ3 = *(const i32x4*)(Ap + (arow + 96) * 16);                              \
  } while (0)

#define MFMA8(A0, A1, A2, A3, KC, PAR) do {                                    \
    acc[0][0] = __builtin_amdgcn_mfma_i32_32x32x32_i8(A0, b[PAR][KC][0], acc[0][0], 0, 0, 0); \
    acc[0][1] = __builtin_amdgcn_mfma_i32_32x32x32_i8(A0, b[PAR][KC][1], acc[0][1], 0, 0, 0); \
    acc[1][0] = __builtin_amdgcn_mfma_i32_32x32x32_i8(A1, b[PAR][KC][0], acc[1][0], 0, 0, 0); \
    acc[1][1] = __builtin_amdgcn_mfma_i32_32x32x32_i8(A1, b[PAR][KC][1], acc[1][1], 0, 0, 0); \
    acc[2][0] = __builtin_amdgcn_mfma_i32_32x32x32_i8(A2, b[PAR][KC][0], acc[2][0], 0, 0, 0); \
    acc[2][1] = __builtin_amdgcn_mfma_i32_32x32x32_i8(A2, b[PAR][KC][1], acc[2][1], 0, 0, 0); \
    acc[3][0] = __builtin_amdgcn_mfma_i32_32x32x32_i8(A3, b[PAR][KC][0], acc[3][0], 0, 0, 0); \
    acc[3][1] = __builtin_amdgcn_mfma_i32_32x32x32_i8(A3, b[PAR][KC][1], acc[3][1], 0, 0, 0); \
  } while (0)

#define MFMA8_P(KC, PAR) MFMA8(aP0, aP1, aP2, aP3, KC, PAR)
#define MFMA8_Q(KC, PAR) MFMA8(aQ0, aQ1, aQ2, aQ3, KC, PAR)

  BLOAD(0, 0);
  BARRIER();                            // matches producer prologue barrier
  for (int s = 0; s < NS; ++s) {        // 16 slot-steps, 8 chunks each
    const unsigned char* slot = &As[s & 1][0];
    const int t0 = s * 4;
    // chunk c: tile J=c>>1 at TOFF=J*16384, KC=c&1, B-parity=J&1.
    // READF for chunk c+1 is issued BEFORE chunk c's MFMAs (latency hiding).
    READF_P(0, 0);                                   // c0 (exposed, post-barrier)
    if (t0 + 1 < NT) BLOAD(1, t0 + 1);
    READF_Q(0, 1);         MFMA8_P(0, 0);            // pre c1, compute c0
    READF_P(16384, 0);     MFMA8_Q(1, 0);            // pre c2, compute c1
    if (t0 + 2 < NT) BLOAD(0, t0 + 2);
    READF_Q(16384, 1);     MFMA8_P(0, 1);            // pre c3, compute c2
    READF_P(32768, 0);     MFMA8_Q(1, 1);            // pre c4, compute c3
    if (t0 + 3 < NT) BLOAD(1, t0 + 3);
    READF_Q(32768, 1);     MFMA8_P(0, 0);            // pre c5, compute c4
    READF_P(49152, 0);     MFMA8_Q(1, 0);            // pre c6, compute c5
    if (t0 + 4 < NT) BLOAD(0, t0 + 4);
    READF_Q(49152, 1);     MFMA8_P(0, 1);            // pre c7, compute c6
                           MFMA8_Q(1, 1);            // compute c7
    BARRIER();                          // slot s free; slot s+1 resident
  }

  // epilogue: C/D layout col=lane&31, row=(r&3)+8*(r>>2)+4*(lane>>5)
  const float alpha = *alphaP;
  const int row0 = br * 256 + cr * 128 + 4 * kgl;
  const int col0 = bc * 128 + cc * 64 + l31;
#pragma unroll
  for (int ni = 0; ni < 2; ++ni) {
    const int col = col0 + ni * 32;
    const float bf = __half2float(bias[col]);
#pragma unroll
    for (int mi = 0; mi < 4; ++mi) {
#pragma unroll
      for (int r = 0; r < 16; ++r) {
        const int row = row0 + mi * 32 + (r & 3) + 8 * (r >> 2);
        out[(size_t)row * N + col] = ((float)acc[mi][ni][r] + bf) * alpha;
      }
    }
  }
#undef MFMA8_P
#undef MFMA8_Q
#undef MFMA8
#undef READF_P
#undef READF_Q
#undef BLOAD
}

extern "C" void kernel_launch(void* const* d_in, const int* in_sizes, int n_in,
                              void* d_out, int out_size, void* d_ws, size_t ws_size,
                              hipStream_t stream) {
  const int*    x     = (const int*)d_in[0];
  const int*    wgt   = (const int*)d_in[1];
  const __half* bias  = (const __half*)d_in[2];
  const float*  alpha = (const float*)d_in[3];
  float*        out   = (float*)d_out;

  // workspace: packed A (32 MB) + packed B (16 MB) = 48 MB
  unsigned char* wa = (unsigned char*)d_ws;
  unsigned char* wb = wa + (size_t)M * K;

  pack_kernel<<<PX_BLOCKS + PW_BLOCKS, 256, 0, stream>>>(x, wgt, wa, wb);

  dim3 grid(N / 128, M / 256);   // 32 x 32 = 1024 blocks
  gemm_i8<<<grid, 512, 0, stream>>>(wa, wb, bias, alpha, out);
}

// Round 27
// 197.454 us; speedup vs baseline: 1.1915x; 1.1915x over previous
//
#include <hip/hip_runtime.h>
#include <hip/hip_fp16.h>

using i32x2  = __attribute__((ext_vector_type(2)))  int;
using i32x4  = __attribute__((ext_vector_type(4)))  int;
using i32x16 = __attribute__((ext_vector_type(16))) int;

static constexpr int M  = 4 * 2048;   // 8192 rows (B*S)
static constexpr int N  = 4096;       // OUT_F
static constexpr int K  = 4096;       // IN_F
static constexpr int NT = K / 64;     // 64 K-tiles
static constexpr int NS = K / 256;    // 16 slots (4 K-tiles each)
static constexpr int ATILE = 256 * 64;  // 16 KB packed A tile (256-row)
static constexpr int BTILE = 128 * 64;  //  8 KB packed B tile (128-col)

// ---------------- fused pack kernel: int32 -> blocked int8 tiles -------------
// A tile (16 KB): [kg(4)][row(256)][16B]   wa: [M/256][NT][ATILE]
// B tile ( 8 KB): [kg(4)][col(128)][16B]   wb: [N/128][NT][BTILE] (transposed)
// pack_x: one block = 64 rows x 64 k; coalesced read, LDS transpose, 1KB-run writes.
static constexpr int PX_BLOCKS = 32 * 4 * 64;                      // 8192
static constexpr int PW_BLOCKS = (int)((size_t)N * K / 16 / 256);  // 4096

__device__ __forceinline__ unsigned pack4(i32x4 v) {
  return (unsigned)((v.x & 255) | ((v.y & 255) << 8) | ((v.z & 255) << 16) | (v.w << 24));
}

__global__ __launch_bounds__(256) void pack_kernel(const int* __restrict__ x,
                                                   const int* __restrict__ w,
                                                   unsigned char* __restrict__ wa,
                                                   unsigned char* __restrict__ wb) {
  __shared__ __align__(16) unsigned char lds[64 * 72];   // 72-B row stride

  if (blockIdx.x < PX_BLOCKS) {
    const int b      = blockIdx.x;
    const int br     = b >> 8;           // 0..31
    const int rowblk = (b >> 6) & 3;     // 0..3  (64-row slab)
    const int kt     = b & 63;           // 0..63 (K-tile)
    const int t      = threadIdx.x;

    // read: thread t -> row (t>>2), k-chunk (t&3)*16; 64 B contiguous per thread
    const int rrow = t >> 2, rch = t & 3;
    const int* src = x + (size_t)(br * 256 + rowblk * 64 + rrow) * K
                       + kt * 64 + rch * 16;
    i32x4 v0 = *(const i32x4*)(src + 0);
    i32x4 v1 = *(const i32x4*)(src + 4);
    i32x4 v2 = *(const i32x4*)(src + 8);
    i32x4 v3 = *(const i32x4*)(src + 12);
    i32x2 lo, hi;
    lo.x = (int)pack4(v0); lo.y = (int)pack4(v1);
    hi.x = (int)pack4(v2); hi.y = (int)pack4(v3);
    *(i32x2*)(lds + rrow * 72 + rch * 16 + 0) = lo;
    *(i32x2*)(lds + rrow * 72 + rch * 16 + 8) = hi;
    __syncthreads();

    // write: thread t -> kg (t>>6), row (t&63); dest contiguous across lanes
    const int kg = t >> 6, wrow = t & 63;
    i32x2 a = *(const i32x2*)(lds + wrow * 72 + kg * 16 + 0);
    i32x2 c = *(const i32x2*)(lds + wrow * 72 + kg * 16 + 8);
    i32x4 d; d.x = a.x; d.y = a.y; d.z = c.x; d.w = c.y;
    unsigned char* dst = wa + (size_t)(br * 64 + kt) * 16384
                            + (kg * 256 + rowblk * 64 + wrow) * 16;
    *(i32x4*)dst = d;
  } else {
    unsigned g = (blockIdx.x - PX_BLOCKS) * 256 + threadIdx.x;  // < N*K/16
    unsigned col = g & 127;
    unsigned kg  = (g >> 7) & 3;
    unsigned kt  = (g >> 9) & 63;
    unsigned bn  = g >> 15;
    unsigned n   = bn * 128 + col;
    unsigned k0  = kt * 64 + kg * 16;
    const int* src = w + (size_t)k0 * N + n;
    i32x4 d;
#pragma unroll
    for (int j = 0; j < 4; ++j) {
      int b0 = src[(size_t)(j * 4 + 0) * N];
      int b1 = src[(size_t)(j * 4 + 1) * N];
      int b2 = src[(size_t)(j * 4 + 2) * N];
      int b3 = src[(size_t)(j * 4 + 3) * N];
      d[j] = (b0 & 255) | ((b1 & 255) << 8) | ((b2 & 255) << 16) | (b3 << 24);
    }
    *(i32x4*)(wb + (size_t)g * 16) = d;
  }
}

// -- GEMM: R23 verbatim (best: gemm 154 us, total 202 us) + XCD-chunk swizzle.
// Producer-consumer, quad-tile slots (BK=256), 2-slot ring, 128 KB LDS.
// Block 256x128, 512 thr. Waves 0-3: consumers (2x2 grid, wave 128x64,
//   acc[4][2]). Waves 4-7: producers (16 gload_lds each). 1 barrier/slot.
// B direct L2->VGPR, parity dbuf per K-tile.
// Swizzle: each XCD (bid&7) owns a compact 4-br x 32-bc chunk, traversed
//   bc-major — resident patch ~4 A-panels + 8 B-panels (~8 MB) instead of
//   the x-major scatter (~12 MB) -> fewer L2/L3 misses, lower FETCH.

__device__ __forceinline__ void gload_lds16(const void* g, void* l) {
  __builtin_amdgcn_global_load_lds((const __attribute__((address_space(1))) unsigned int*)g,
                                   (__attribute__((address_space(3))) unsigned int*)l,
                                   16, 0, 0);
}

#define FENCE()   asm volatile("" ::: "memory")
#define BARRIER() do { FENCE(); __builtin_amdgcn_s_barrier(); FENCE(); } while (0)

__global__ __launch_bounds__(512, 1) void gemm_i8(const unsigned char* __restrict__ wa,
                                                  const unsigned char* __restrict__ wb,
                                                  const __half* __restrict__ bias,
                                                  const float* __restrict__ alphaP,
                                                  float* __restrict__ out) {
  __shared__ __align__(16) unsigned char As[2][65536];   // 128 KB: 2 slots x 4 A-tiles

  const int tid  = threadIdx.x;
  const int lane = tid & 63;
  const int w    = tid >> 6;            // wave 0..7
  const int cw   = w & 3;
  const int l31  = lane & 31;
  const int kgl  = lane >> 5;

  // XCD-chunk swizzle: bijective (1024 blocks, 1024 % 8 == 0).
  const int bid = blockIdx.x;
  const int swz = (bid & 7) * 128 + (bid >> 3);   // [0,1024)
  const int xg  = swz >> 7;                       // XCD chunk 0..7
  const int sub = swz & 127;
  const int brl = sub & 3;                        // local br 0..3
  const int bc  = sub >> 2;                       // 0..31 (N/128)
  const int br  = xg * 4 + brl;                   // 0..31 (M/256)

  const unsigned char* ga = wa + (size_t)br * NT * ATILE;   // 256-row A panel

  if (w >= 4) {
    // ------------------------- PRODUCER (1 per SIMD) -----------------------
    const int poff = cw * 16384;        // this wave's 16 KB of the 64 KB slot

#define STAGE(S) do {                                                          \
      const unsigned char* src = ga + (size_t)(S) * 65536 + poff + lane * 16;  \
      unsigned char* dst = &As[(S) & 1][poff];                                 \
      _Pragma("unroll")                                                        \
      for (int j = 0; j < 16; ++j)                                             \
        gload_lds16(src + j * 1024, dst + j * 1024);                           \
    } while (0)

    STAGE(0);
    asm volatile("s_waitcnt vmcnt(0)" ::: "memory");
    BARRIER();                           // slot 0 ready
    for (int s = 0; s < NS; ++s) {
      if (s + 1 < NS) {
        STAGE(s + 1);                    // slot (s+1)&1 was freed at barrier s-1
        asm volatile("s_waitcnt vmcnt(0)" ::: "memory");
      }
      BARRIER();                         // end of step s: slot s+1 resident
    }
#undef STAGE
    return;   // producers skip epilogue
  }

  // --------------------------- CONSUMER (1 per SIMD) -----------------------
  const int cr = cw >> 1, cc = cw & 1;  // 2 x 2 grid; wave tile 128 x 64
  const int arow = cr * 128 + l31;      // A frag row base
  const int bcol = cc * 64 + l31;       // B frag col base (within 128-panel)

  const unsigned char* gbw = wb + (size_t)bc * NT * BTILE;  // 128-col B panel

  i32x4 b[2][2][2];                     // [parity][kc][ni] — const indices
  i32x16 acc[4][2] = {};

#define BLOAD(PAR, T) do {                                                     \
    const unsigned char* bt = gbw + (size_t)(T) * BTILE;                       \
    b[PAR][0][0] = *(const i32x4*)(bt + (kgl)     * 2048 + (bcol +  0) * 16);  \
    b[PAR][0][1] = *(const i32x4*)(bt + (kgl)     * 2048 + (bcol + 32) * 16);  \
    b[PAR][1][0] = *(const i32x4*)(bt + (2 + kgl) * 2048 + (bcol +  0) * 16);  \
    b[PAR][1][1] = *(const i32x4*)(bt + (2 + kgl) * 2048 + (bcol + 32) * 16);  \
  } while (0)

#define CHUNK(TOFF, KC, PAR) do {                                              \
    const unsigned char* Ap = slot + (TOFF) + ((KC) * 2 + kgl) * 4096;         \
    i32x4 a0 = *(const i32x4*)(Ap + (arow +  0) * 16);                         \
    i32x4 a1 = *(const i32x4*)(Ap + (arow + 32) * 16);                         \
    i32x4 a2 = *(const i32x4*)(Ap + (arow + 64) * 16);                         \
    i32x4 a3 = *(const i32x4*)(Ap + (arow + 96) * 16);                         \
    acc[0][0] = __builtin_amdgcn_mfma_i32_32x32x32_i8(a0, b[PAR][KC][0], acc[0][0], 0, 0, 0); \
    acc[0][1] = __builtin_amdgcn_mfma_i32_32x32x32_i8(a0, b[PAR][KC][1], acc[0][1], 0, 0, 0); \
    acc[1][0] = __builtin_amdgcn_mfma_i32_32x32x32_i8(a1, b[PAR][KC][0], acc[1][0], 0, 0, 0); \
    acc[1][1] = __builtin_amdgcn_mfma_i32_32x32x32_i8(a1, b[PAR][KC][1], acc[1][1], 0, 0, 0); \
    acc[2][0] = __builtin_amdgcn_mfma_i32_32x32x32_i8(a2, b[PAR][KC][0], acc[2][0], 0, 0, 0); \
    acc[2][1] = __builtin_amdgcn_mfma_i32_32x32x32_i8(a2, b[PAR][KC][1], acc[2][1], 0, 0, 0); \
    acc[3][0] = __builtin_amdgcn_mfma_i32_32x32x32_i8(a3, b[PAR][KC][0], acc[3][0], 0, 0, 0); \
    acc[3][1] = __builtin_amdgcn_mfma_i32_32x32x32_i8(a3, b[PAR][KC][1], acc[3][1], 0, 0, 0); \
  } while (0)

  // per K-tile j within the slot (par = j&1, compile-time after unroll):
  // prefetch B(tt+1) into par^1, then 2 chunks (16 MFMAs) on tile j.
#define TILE_J(S, J) do {                                                      \
    const int tt = (S) * 4 + (J);                                              \
    if (tt + 1 < NT) BLOAD(((J) + 1) & 1, tt + 1);                             \
    __builtin_amdgcn_s_setprio(1);                                             \
    CHUNK((J) * 16384, 0, (J) & 1);                                            \
    CHUNK((J) * 16384, 1, (J) & 1);                                            \
    __builtin_amdgcn_s_setprio(0);                                             \
  } while (0)

  BLOAD(0, 0);
  BARRIER();                            // matches producer prologue barrier
  for (int s = 0; s < NS; ++s) {        // 16 slot-steps
    const unsigned char* slot = &As[s & 1][0];
    TILE_J(s, 0);
    TILE_J(s, 1);
    TILE_J(s, 2);
    TILE_J(s, 3);
    BARRIER();                          // slot s free; slot s+1 resident
  }

  // epilogue: C/D layout col=lane&31, row=(r&3)+8*(r>>2)+4*(lane>>5)
  const float alpha = *alphaP;
  const int row0 = br * 256 + cr * 128 + 4 * kgl;
  const int col0 = bc * 128 + cc * 64 + l31;
#pragma unroll
  for (int ni = 0; ni < 2; ++ni) {
    const int col = col0 + ni * 32;
    const float bf = __half2float(bias[col]);
#pragma unroll
    for (int mi = 0; mi < 4; ++mi) {
#pragma unroll
      for (int r = 0; r < 16; ++r) {
        const int row = row0 + mi * 32 + (r & 3) + 8 * (r >> 2);
        out[(size_t)row * N + col] = ((float)acc[mi][ni][r] + bf) * alpha;
      }
    }
  }
#undef TILE_J
#undef CHUNK
#undef BLOAD
}

extern "C" void kernel_launch(void* const* d_in, const int* in_sizes, int n_in,
                              void* d_out, int out_size, void* d_ws, size_t ws_size,
                              hipStream_t stream) {
  const int*    x     = (const int*)d_in[0];
  const int*    wgt   = (const int*)d_in[1];
  const __half* bias  = (const __half*)d_in[2];
  const float*  alpha = (const float*)d_in[3];
  float*        out   = (float*)d_out;

  // workspace: packed A (32 MB) + packed B (16 MB) = 48 MB
  unsigned char* wa = (unsigned char*)d_ws;
  unsigned char* wb = wa + (size_t)M * K;

  pack_kernel<<<PX_BLOCKS + PW_BLOCKS, 256, 0, stream>>>(x, wgt, wa, wb);

  gemm_i8<<<1024, 512, 0, stream>>>(wa, wb, bias, alpha, out);
}